// Round 2
// baseline (419.287 us; speedup 1.0000x reference)
//
#include <hip/hip_runtime.h>
#include <stdint.h>

#define ALPHA 0.2f
#define LOG2E 1.44269504088896340736f

typedef __attribute__((ext_vector_type(8))) short bf16x8;
typedef __attribute__((ext_vector_type(4))) float f32x4;

__device__ __forceinline__ unsigned short f2bf(float f) {
    unsigned u = __builtin_bit_cast(unsigned, f);
    u += 0x7fffu + ((u >> 16) & 1u);
    return (unsigned short)(u >> 16);
}
__device__ __forceinline__ float bf2f(unsigned short h) {
    unsigned u = ((unsigned)h) << 16;
    return __builtin_bit_cast(float, u);
}
// order-preserving float<->uint for atomicMax over signed floats (0 = -inf identity)
__device__ __forceinline__ unsigned f2ord(float f) {
    unsigned b = __builtin_bit_cast(unsigned, f);
    return (b & 0x80000000u) ? ~b : (b | 0x80000000u);
}
__device__ __forceinline__ float ord2f(unsigned k) {
    unsigned b = (k & 0x80000000u) ? (k & 0x7fffffffu) : ~k;
    return __builtin_bit_cast(float, b);
}

// ---------------------------------------------------------------------------
// Kernel 1 (FUSED h+aux): one block = 16 rows, full K=512. h lives only in
// LDS: computes attL/attR (+wsR max) and hPack fragments directly.
// Eliminates global h (2 MB write + 2 MB read), its memset, 2M k-split
// atomics, and one dispatch vs the R1 version.
__global__ __launch_bounds__(256) void gat_pre(
    const float* __restrict__ input, const float* __restrict__ W,
    const float* __restrict__ a,
    float* __restrict__ attL, float* __restrict__ attR,
    unsigned short* __restrict__ hPack, unsigned* __restrict__ wsR)
{
    __shared__ float x_lds[16 * 512];   // 32 KB input tile
    __shared__ float h_lds[16 * 64];    // 4 KB h tile
    __shared__ unsigned rmax;
    const int tid = threadIdx.x;
    const int i0  = blockIdx.x * 16;
    if (tid == 0) rmax = 0u;

    // stage input tile 16x512 (flat row-major == global layout, fully coalesced)
    {
        const float* src = input + (size_t)i0 * 512;
        #pragma unroll
        for (int u = 0; u < 8; ++u) {
            const int f = (u * 256 + tid) * 4;
            *(f32x4*)&x_lds[f] = *(const f32x4*)(src + f);
        }
    }
    __syncthreads();

    // h tile: thread (c = tid&63, w = tid>>6) computes rows w+4*ri, col c.
    // x_lds read is a wave-broadcast (same addr across the 64 lanes of a
    // c-group); W load is one coalesced 256B line per k.
    {
        const int c = tid & 63;
        const int w = tid >> 6;
        float acc[4] = {0.f, 0.f, 0.f, 0.f};
        const float* Wc = W + c;
        #pragma unroll 4
        for (int kk = 0; kk < 512; kk += 4) {
            const float w0 = Wc[(kk+0)*64], w1 = Wc[(kk+1)*64];
            const float w2 = Wc[(kk+2)*64], w3 = Wc[(kk+3)*64];
            #pragma unroll
            for (int ri = 0; ri < 4; ++ri) {
                const f32x4 x = *(const f32x4*)&x_lds[(w + 4*ri) * 512 + kk];
                acc[ri] += x.x * w0 + x.y * w1 + x.z * w2 + x.w * w3;
            }
        }
        #pragma unroll
        for (int ri = 0; ri < 4; ++ri)
            h_lds[(w + 4*ri) * 64 + c] = acc[ri];
    }
    __syncthreads();

    if (tid < 128) {
        // waves 0-1: attL/attR for the 16 rows (8 threads per row)
        const int row = tid >> 3;
        const int cs  = (tid & 7) * 8;
        float pL = 0.f, pR = 0.f;
        #pragma unroll
        for (int u = 0; u < 8; ++u) {
            const float hv = h_lds[row * 64 + cs + u];
            pL += hv * a[cs + u];
            pR += hv * a[64 + cs + u];
        }
        pL += __shfl_xor(pL, 1, 64); pR += __shfl_xor(pR, 1, 64);
        pL += __shfl_xor(pL, 2, 64); pR += __shfl_xor(pR, 2, 64);
        pL += __shfl_xor(pL, 4, 64); pR += __shfl_xor(pR, 4, 64);
        if ((tid & 7) == 0) {
            attL[i0 + row] = pL;
            attR[i0 + row] = pR;
            atomicMax(&rmax, f2ord(pR));
        }
    } else {
        // waves 2-3: hPack fragments for these 16 rows (half of a 32-row
        // hPack block). hPack lane l = q*16+m, elem u -> h row q*8+u (local
        // to the 32-row block), col g*16+m. Our tile is half = (i0/16)&1,
        // i.e. q = half*2 + qq, local row qq*8+u.
        const int t2   = tid - 128;
        const int g    = t2 >> 5;
        const int qq   = (t2 >> 4) & 1;
        const int m    = t2 & 15;
        const int jb   = blockIdx.x >> 1;
        const int half = blockIdx.x & 1;
        bf16x8 v;
        #pragma unroll
        for (int u = 0; u < 8; ++u)
            v[u] = (short)f2bf(h_lds[(qq * 8 + u) * 64 + g * 16 + m]);
        *(bf16x8*)&hPack[(size_t)(jb * 4 + g) * 512 + ((half * 2 + qq) * 16 + m) * 8] = v;
    }

    __syncthreads();
    if (tid == 0) atomicMax(wsR, rmax);
}

// ---------------------------------------------------------------------------
// Kernel 2 (FUSED pack+attn): reads raw adj coalesced, packs bitmask into LDS
// (per-wave 1 KB bit regions at 4 KB stride, aliasing each wave's own later
// acc-epilogue region), then identical phase-2 MFMA loop as R4.
// Block: 16 i-rows x 2048 j. 2048 blocks.
__global__ __launch_bounds__(256, 4) void gat_attn(
    const int* __restrict__ adj,
    const float* __restrict__ attL, const float* __restrict__ attR,
    const unsigned short* __restrict__ hPack, const unsigned* __restrict__ wsR,
    float* __restrict__ outAcc, float* __restrict__ lAcc)
{
    __shared__ unsigned smem[4096];   // phase1: bitmask words; phase2 epilogue: acc floats
    __shared__ float l_lds[64];
    const int tid  = threadIdx.x;
    const int lane = tid & 63;
    const int wq   = tid >> 6;
    const int m    = lane & 15;
    const int quad = lane >> 4;
    const int ti   = blockIdx.x >> 2;
    const int q4   = blockIdx.x & 3;
    const int i0   = ti * 16;
    const int jc0  = q4 * 64 + wq * 16;     // wave's first 32-j chunk (global units)

    // ---- phase 1: pack adj[i0..i0+16)[q4*2048..+2048) -> LDS bitmask ----
    // thread covers row r = tid>>4, col octets (tid&15)*8 + it*128.
    // byte (G_local=it, t=(tid&15)>>2, frag-lane=(tid&3)*16+r) stored at
    // uint (it>>2)*1024 + (it&3)*64 + lane, byte t.  (R4-verified mapping)
    {
        const int r    = tid >> 4;
        const int lidx = (tid & 3) * 16 + r;
        const int t    = (tid & 15) >> 2;
        unsigned char* bb = (unsigned char*)smem;
        const int* src = adj + (size_t)(i0 + r) * 8192 + q4 * 2048 + (tid & 15) * 8;
        #pragma unroll 4
        for (int it = 0; it < 16; ++it) {
            const int4 v0 = *(const int4*)(src + it * 128);
            const int4 v1 = *(const int4*)(src + it * 128 + 4);
            unsigned b = 0;
            b |= (v0.x != 0) << 0; b |= (v0.y != 0) << 1;
            b |= (v0.z != 0) << 2; b |= (v0.w != 0) << 3;
            b |= (v1.x != 0) << 4; b |= (v1.y != 0) << 5;
            b |= (v1.z != 0) << 6; b |= (v1.w != 0) << 7;
            bb[((((it >> 2) * 1024) + (it & 3) * 64 + lidx) << 2) + t] = (unsigned char)b;
        }
    }
    __syncthreads();

    // preload this wave's 4 bit-words (its own 1 KB region; safe to overwrite
    // later by its own acc epilogue — program order within the wave)
    unsigned abw[4];
    #pragma unroll
    for (int g4 = 0; g4 < 4; ++g4)
        abw[g4] = smem[wq * 1024 + g4 * 64 + lane];

    const float R   = ord2f(*wsR);
    const float a_l = attL[i0 + m];
    const float t0  = a_l + R;
    const float M   = fmaxf(t0, ALPHA * t0);   // row upper bound (lrelu monotone)
    const float mc  = M * LOG2E;

    const float*          ar_p = attR + jc0 * 32 + quad * 8;
    const unsigned short* hp_p = hPack + (size_t)jc0 * 4 * 512 + lane * 8;

    f32x4 acc[4];
    #pragma unroll
    for (int g = 0; g < 4; ++g) acc[g] = (f32x4){0.f, 0.f, 0.f, 0.f};
    float lsum = 0.f;

    #pragma unroll
    for (int jg = 0; jg < 4; ++jg) {
        const unsigned ab = abw[jg];            // 4 steps' bits
        #pragma unroll
        for (int t = 0; t < 4; ++t) {
            const int s = jg * 4 + t;
            const f32x4 r0 = *(const f32x4*)(ar_p + s * 32);
            const f32x4 r1 = *(const f32x4*)(ar_p + s * 32 + 4);
            bf16x8 B[4];
            #pragma unroll
            for (int g = 0; g < 4; ++g)
                B[g] = *(const bf16x8*)(hp_p + (size_t)(s * 4 + g) * 512);

            const unsigned bits = (ab >> (t * 8)) & 0xffu;
            const float tv[8] = { a_l + r0.x, a_l + r0.y, a_l + r0.z, a_l + r0.w,
                                  a_l + r1.x, a_l + r1.y, a_l + r1.z, a_l + r1.w };
            bf16x8 af;
            #pragma unroll
            for (int u = 0; u < 8; ++u) {
                const float e  = fmaxf(tv[u], ALPHA * tv[u]);        // leaky_relu
                const float pe = __builtin_amdgcn_exp2f(__builtin_fmaf(e, LOG2E, -mc));
                const float pv = (bits & (1u << u)) ? pe : 0.0f;     // mask
                const unsigned short pb = f2bf(pv);
                af[u] = (short)pb;
                lsum += bf2f(pb);   // denominator from the SAME rounded weights
            }
            #pragma unroll
            for (int g = 0; g < 4; ++g)
                acc[g] = __builtin_amdgcn_mfma_f32_16x16x32_bf16(af, B[g], acc[g], 0, 0, 0);
        }
    }

    // reduce l across the 4 k-quads (row m lives in lanes m, m+16, m+32, m+48)
    lsum += __shfl_xor(lsum, 16, 64);
    lsum += __shfl_xor(lsum, 32, 64);
    if (lane < 16) l_lds[wq * 16 + lane] = lsum;
    // epilogue: wave wq writes floats [wq*1024, +1024) — its own aliased region
    float* accf = (float*)smem;
    #pragma unroll
    for (int g = 0; g < 4; ++g)
        *(f32x4*)&accf[(wq * 64 + lane) * 16 + g * 4] = acc[g];
    __syncthreads();

    // combine 4 waves, scatter partial numerator to global accumulator
    #pragma unroll
    for (int q = 0; q < 4; ++q) {
        const int e      = tid + q * 256;
        const int lane_e = e >> 4;
        const int k16    = e & 15;
        float s = 0.f;
        #pragma unroll
        for (int ww = 0; ww < 4; ++ww) s += accf[(ww * 64 + lane_e) * 16 + k16];
        const int row = (lane_e >> 4) * 4 + (k16 & 3);   // C/D: row = quad*4+reg
        const int col = (k16 >> 2) * 16 + (lane_e & 15); // C/D: col = lane&15 per n-group
        unsafeAtomicAdd(&outAcc[(size_t)(i0 + row) * 64 + col], s);
    }
    if (tid < 16) {
        const float s = l_lds[tid] + l_lds[16 + tid] + l_lds[32 + tid] + l_lds[48 + tid];
        unsafeAtomicAdd(&lAcc[i0 + tid], s);
    }
}

// ---------------------------------------------------------------------------
// Kernel 3: out = elu(numerator / denominator)
__global__ __launch_bounds__(256) void gat_final(
    float* __restrict__ out, const float* __restrict__ lAcc)
{
    const int idx = blockIdx.x * 256 + threadIdx.x;
    const float v = out[idx] / lAcc[idx >> 6];
    out[idx] = v > 0.f ? v : (__builtin_amdgcn_exp2f(v * LOG2E) - 1.0f);
}

extern "C" void kernel_launch(void* const* d_in, const int* in_sizes, int n_in,
                              void* d_out, int out_size, void* d_ws, size_t ws_size,
                              hipStream_t stream) {
    const float* input = (const float*)d_in[0];   // 8192 x 512 f32
    const int*   adj   = (const int*)d_in[1];     // 8192 x 8192 i32
    const float* W     = (const float*)d_in[2];   // 512 x 64 f32
    const float* a     = (const float*)d_in[3];   // 128 x 1 f32
    float* out = (float*)d_out;                   // 8192 x 64 f32

    char* ws = (char*)d_ws;
    unsigned*       wsR   = (unsigned*)(ws + 0);            // 4 B    [zeroed]
    float*          lAcc  = (float*)(ws + 4096);            // 32 KB  [zeroed]
    float*          attL  = (float*)(ws + 2134016);         // 32 KB
    float*          attR  = (float*)(ws + 2166784);         // 32 KB
    unsigned short* hPack = (unsigned short*)(ws + 2199552);// 1 MB   fragment-major h^T bf16

    hipMemsetAsync(d_out, 0, (size_t)out_size * sizeof(float), stream);
    hipMemsetAsync(d_ws, 0, 36864, stream);     // wsR + lAcc only (h is gone)

    gat_pre  <<< 512, 256, 0, stream>>>(input, W, a, attL, attR, hPack, wsR);
    gat_attn <<<2048, 256, 0, stream>>>(adj, attL, attR, hPack, wsR, out, lAcc);
    gat_final<<<2048, 256, 0, stream>>>(out, lAcc);
}

// Round 3
// 416.549 us; speedup vs baseline: 1.0066x; 1.0066x over previous
//
#include <hip/hip_runtime.h>
#include <stdint.h>

#define ALPHA 0.2f
#define LOG2E 1.44269504088896340736f

typedef __attribute__((ext_vector_type(8))) short bf16x8;
typedef __attribute__((ext_vector_type(4))) float f32x4;

__device__ __forceinline__ unsigned short f2bf(float f) {
    unsigned u = __builtin_bit_cast(unsigned, f);
    u += 0x7fffu + ((u >> 16) & 1u);
    return (unsigned short)(u >> 16);
}
__device__ __forceinline__ float bf2f(unsigned short h) {
    unsigned u = ((unsigned)h) << 16;
    return __builtin_bit_cast(float, u);
}
// order-preserving float<->uint for atomicMax over signed floats (0 = -inf identity)
__device__ __forceinline__ unsigned f2ord(float f) {
    unsigned b = __builtin_bit_cast(unsigned, f);
    return (b & 0x80000000u) ? ~b : (b | 0x80000000u);
}
__device__ __forceinline__ float ord2f(unsigned k) {
    unsigned b = (k & 0x80000000u) ? (k & 0x7fffffffu) : ~k;
    return __builtin_bit_cast(float, b);
}

// ---------------------------------------------------------------------------
// Kernel 1 (FUSED h+aux): one block = 16 rows, full K=512. h lives only in
// LDS: computes attL/attR (+wsR max) and hPack fragments directly.
__global__ __launch_bounds__(256) void gat_pre(
    const float* __restrict__ input, const float* __restrict__ W,
    const float* __restrict__ a,
    float* __restrict__ attL, float* __restrict__ attR,
    unsigned short* __restrict__ hPack, unsigned* __restrict__ wsR)
{
    __shared__ float x_lds[16 * 512];   // 32 KB input tile
    __shared__ float h_lds[16 * 64];    // 4 KB h tile
    __shared__ unsigned rmax;
    const int tid = threadIdx.x;
    const int i0  = blockIdx.x * 16;
    if (tid == 0) rmax = 0u;

    // stage input tile 16x512 (flat row-major == global layout, fully coalesced)
    {
        const float* src = input + (size_t)i0 * 512;
        #pragma unroll
        for (int u = 0; u < 8; ++u) {
            const int f = (u * 256 + tid) * 4;
            *(f32x4*)&x_lds[f] = *(const f32x4*)(src + f);
        }
    }
    __syncthreads();

    // h tile: thread (c = tid&63, w = tid>>6) computes rows w+4*ri, col c.
    {
        const int c = tid & 63;
        const int w = tid >> 6;
        float acc[4] = {0.f, 0.f, 0.f, 0.f};
        const float* Wc = W + c;
        #pragma unroll 4
        for (int kk = 0; kk < 512; kk += 4) {
            const float w0 = Wc[(kk+0)*64], w1 = Wc[(kk+1)*64];
            const float w2 = Wc[(kk+2)*64], w3 = Wc[(kk+3)*64];
            #pragma unroll
            for (int ri = 0; ri < 4; ++ri) {
                const f32x4 x = *(const f32x4*)&x_lds[(w + 4*ri) * 512 + kk];
                acc[ri] += x.x * w0 + x.y * w1 + x.z * w2 + x.w * w3;
            }
        }
        #pragma unroll
        for (int ri = 0; ri < 4; ++ri)
            h_lds[(w + 4*ri) * 64 + c] = acc[ri];
    }
    __syncthreads();

    if (tid < 128) {
        // waves 0-1: attL/attR for the 16 rows (8 threads per row)
        const int row = tid >> 3;
        const int cs  = (tid & 7) * 8;
        float pL = 0.f, pR = 0.f;
        #pragma unroll
        for (int u = 0; u < 8; ++u) {
            const float hv = h_lds[row * 64 + cs + u];
            pL += hv * a[cs + u];
            pR += hv * a[64 + cs + u];
        }
        pL += __shfl_xor(pL, 1, 64); pR += __shfl_xor(pR, 1, 64);
        pL += __shfl_xor(pL, 2, 64); pR += __shfl_xor(pR, 2, 64);
        pL += __shfl_xor(pL, 4, 64); pR += __shfl_xor(pR, 4, 64);
        if ((tid & 7) == 0) {
            attL[i0 + row] = pL;
            attR[i0 + row] = pR;
            atomicMax(&rmax, f2ord(pR));
        }
    } else {
        // waves 2-3: hPack fragments for these 16 rows (half of a 32-row
        // hPack block). hPack lane l = q*16+m, elem u -> h row q*8+u (local
        // to the 32-row block), col g*16+m. Our tile is half = blockIdx&1.
        const int t2   = tid - 128;
        const int g    = t2 >> 5;
        const int qq   = (t2 >> 4) & 1;
        const int m    = t2 & 15;
        const int jb   = blockIdx.x >> 1;
        const int half = blockIdx.x & 1;
        bf16x8 v;
        #pragma unroll
        for (int u = 0; u < 8; ++u)
            v[u] = (short)f2bf(h_lds[(qq * 8 + u) * 64 + g * 16 + m]);
        *(bf16x8*)&hPack[(size_t)(jb * 4 + g) * 512 + ((half * 2 + qq) * 16 + m) * 8] = v;
    }

    __syncthreads();
    if (tid == 0) atomicMax(wsR, rmax);
}

// ---------------------------------------------------------------------------
// Kernel 2 (full-row fused attn): one block = 16 i-rows x ALL 8192 j.
// 512 blocks x 512 threads (8 waves); each wave owns j in [wq*1024,+1024)
// (32 s-steps of 32 j). j is the MFMA contraction dim, so acc stays 4xf32x4.
// Softmax denominator completes in-block -> divide + ELU fused, out written
// directly. No atomics, no out/lAcc memsets, no final kernel.
//
// Bitmask mapping (re-derived for 8-wave geometry, bijective):
//   consume: bit for (row m, block-local j): wq=j>>10, s=(j>>5)&31,
//            word g=s>>2 (abw[g]), byte t=s&3, lane=((j>>3)&3)*16+m, bit j&7.
//            abw[g] = smem[wq*512 + g*64 + lane].
//   produce: thread r=tid>>5, o=tid&31; it in 0..31 covers j0=o*8+it*256:
//            wq=it>>2, g=(o>>4)+(it&3)*2, t=(o>>2)&3, lane=(o&3)*16+r.
__global__ __launch_bounds__(512, 4) void gat_attn(
    const int* __restrict__ adj,
    const float* __restrict__ attL, const float* __restrict__ attR,
    const unsigned short* __restrict__ hPack, const unsigned* __restrict__ wsR,
    float* __restrict__ out)
{
    __shared__ unsigned smem[8192];   // phase1: 16KB bitmask (first 4096); epilogue: 32KB acc floats
    __shared__ float l_lds[128];
    const int tid  = threadIdx.x;
    const int lane = tid & 63;
    const int wq   = tid >> 6;
    const int m    = lane & 15;
    const int quad = lane >> 4;
    const int i0   = blockIdx.x * 16;

    // ---- phase 1: pack adj[i0..i0+16)[0..8192) -> LDS bitmask (16 KB) ----
    {
        const int r      = tid >> 5;
        const int o      = tid & 31;
        const int lane_s = (o & 3) * 16 + r;
        const int tb     = (o >> 2) & 3;
        const int gbase  = o >> 4;
        unsigned char* bb = (unsigned char*)smem;
        const int* src = adj + (size_t)(i0 + r) * 8192 + o * 8;
        #pragma unroll 4
        for (int it = 0; it < 32; ++it) {
            const int4 v0 = *(const int4*)(src + it * 256);
            const int4 v1 = *(const int4*)(src + it * 256 + 4);
            unsigned b = 0;
            b |= (v0.x != 0) << 0; b |= (v0.y != 0) << 1;
            b |= (v0.z != 0) << 2; b |= (v0.w != 0) << 3;
            b |= (v1.x != 0) << 4; b |= (v1.y != 0) << 5;
            b |= (v1.z != 0) << 6; b |= (v1.w != 0) << 7;
            const int idx = (it >> 2) * 512 + (gbase + (it & 3) * 2) * 64 + lane_s;
            bb[(idx << 2) + tb] = (unsigned char)b;
        }
    }
    __syncthreads();

    // preload this wave's 8 bit-words into registers
    unsigned abw[8];
    #pragma unroll
    for (int g = 0; g < 8; ++g)
        abw[g] = smem[wq * 512 + g * 64 + lane];
    __syncthreads();   // all preloads done before any epilogue write aliases smem

    const float R   = ord2f(*wsR);
    const float a_l = attL[i0 + m];
    const float t0  = a_l + R;
    const float M   = fmaxf(t0, ALPHA * t0);   // row upper bound (lrelu monotone)
    const float mc  = M * LOG2E;

    const int jc0 = wq * 32;                   // wave's first 32-j chunk
    const float*          ar_p = attR + jc0 * 32 + quad * 8;
    const unsigned short* hp_p = hPack + (size_t)jc0 * 4 * 512 + lane * 8;

    f32x4 acc[4];
    #pragma unroll
    for (int g = 0; g < 4; ++g) acc[g] = (f32x4){0.f, 0.f, 0.f, 0.f};
    float lsum = 0.f;

    #pragma unroll
    for (int jg = 0; jg < 8; ++jg) {
        const unsigned ab = abw[jg];            // 4 steps' bits
        #pragma unroll
        for (int t = 0; t < 4; ++t) {
            const int s = jg * 4 + t;
            const f32x4 r0 = *(const f32x4*)(ar_p + s * 32);
            const f32x4 r1 = *(const f32x4*)(ar_p + s * 32 + 4);
            bf16x8 B[4];
            #pragma unroll
            for (int g = 0; g < 4; ++g)
                B[g] = *(const bf16x8*)(hp_p + (size_t)(s * 4 + g) * 512);

            const unsigned bits = (ab >> (t * 8)) & 0xffu;
            const float tv[8] = { a_l + r0.x, a_l + r0.y, a_l + r0.z, a_l + r0.w,
                                  a_l + r1.x, a_l + r1.y, a_l + r1.z, a_l + r1.w };
            bf16x8 af;
            #pragma unroll
            for (int u = 0; u < 8; ++u) {
                const float e  = fmaxf(tv[u], ALPHA * tv[u]);        // leaky_relu
                const float pe = __builtin_amdgcn_exp2f(__builtin_fmaf(e, LOG2E, -mc));
                const float pv = (bits & (1u << u)) ? pe : 0.0f;     // mask
                const unsigned short pb = f2bf(pv);
                af[u] = (short)pb;
                lsum += bf2f(pb);   // denominator from the SAME rounded weights
            }
            #pragma unroll
            for (int g = 0; g < 4; ++g)
                acc[g] = __builtin_amdgcn_mfma_f32_16x16x32_bf16(af, B[g], acc[g], 0, 0, 0);
        }
    }

    // reduce l across the 4 k-quads (row m lives in lanes m, m+16, m+32, m+48)
    lsum += __shfl_xor(lsum, 16, 64);
    lsum += __shfl_xor(lsum, 32, 64);
    if (lane < 16) l_lds[wq * 16 + lane] = lsum;
    // epilogue: wave wq writes floats [wq*1024, +1024) — aliases bitmask
    // region, safe: all abw preloads completed before the barrier above
    float* accf = (float*)smem;
    #pragma unroll
    for (int g = 0; g < 4; ++g)
        *(f32x4*)&accf[(wq * 64 + lane) * 16 + g * 4] = acc[g];
    __syncthreads();

    // combine 8 waves, finish softmax (divide) + ELU, write out directly
    #pragma unroll
    for (int q = 0; q < 2; ++q) {
        const int e      = tid + q * 512;
        const int lane_e = e >> 4;
        const int k16    = e & 15;
        float s = 0.f;
        #pragma unroll
        for (int ww = 0; ww < 8; ++ww) s += accf[(ww * 64 + lane_e) * 16 + k16];
        const int row = (lane_e >> 4) * 4 + (k16 & 3);   // C/D: row = quad*4+reg
        const int col = (k16 >> 2) * 16 + (lane_e & 15); // C/D: col = lane&15 per n-group
        float l = 0.f;
        #pragma unroll
        for (int ww = 0; ww < 8; ++ww) l += l_lds[ww * 16 + row];
        const float v = s / l;
        out[(size_t)(i0 + row) * 64 + col] =
            v > 0.f ? v : (__builtin_amdgcn_exp2f(v * LOG2E) - 1.0f);
    }
}

extern "C" void kernel_launch(void* const* d_in, const int* in_sizes, int n_in,
                              void* d_out, int out_size, void* d_ws, size_t ws_size,
                              hipStream_t stream) {
    const float* input = (const float*)d_in[0];   // 8192 x 512 f32
    const int*   adj   = (const int*)d_in[1];     // 8192 x 8192 i32
    const float* W     = (const float*)d_in[2];   // 512 x 64 f32
    const float* a     = (const float*)d_in[3];   // 128 x 1 f32
    float* out = (float*)d_out;                   // 8192 x 64 f32

    char* ws = (char*)d_ws;
    unsigned*       wsR   = (unsigned*)(ws + 0);            // 4 B    [zeroed]
    float*          attL  = (float*)(ws + 2134016);         // 32 KB
    float*          attR  = (float*)(ws + 2166784);         // 32 KB
    unsigned short* hPack = (unsigned short*)(ws + 2199552);// 1 MB   fragment-major h^T bf16

    hipMemsetAsync(d_ws, 0, 4096, stream);   // wsR only

    gat_pre  <<< 512, 256, 0, stream>>>(input, W, a, attL, attR, hPack, wsR);
    gat_attn <<< 512, 512, 0, stream>>>(adj, attL, attR, hPack, wsR, out);
}